// Round 1
// baseline (438.820 us; speedup 1.0000x reference)
//
#include <hip/hip_runtime.h>
#include <hip/hip_bf16.h>

// Problem constants
#define B_    2
#define T_    2048
#define C_    2048
#define H_    32
#define HKV_  8
#define DH_   64
#define NROW  4096      // B*T
#define NQKV  3072      // C + 2*HKV*DH
#define KOFF  2048      // k columns start
#define VOFF  2560      // v columns start

typedef __attribute__((ext_vector_type(4))) float f32x4;
typedef __attribute__((ext_vector_type(8))) short bf16x8;
typedef __attribute__((ext_vector_type(4))) short s16x4;

__device__ __forceinline__ float bf2f(short s) {
  union { unsigned u; float f; } v; v.u = ((unsigned)(unsigned short)s) << 16; return v.f;
}
__device__ __forceinline__ short f2bf(float f) {
  union { float f; unsigned u; } v; v.f = f;
  unsigned u = v.u + 0x7fffu + ((v.u >> 16) & 1u);   // RNE
  return (short)(u >> 16);
}

__device__ __forceinline__ void gload_lds16(const void* g, void* l) {
  __builtin_amdgcn_global_load_lds((const __attribute__((address_space(1))) void*)g,
                                   (__attribute__((address_space(3))) void*)l, 16, 0, 0);
}

// ---------------- fp32 -> bf16 convert ----------------
__global__ void cvt_kernel(const float* __restrict__ src, short* __restrict__ dst, int n4) {
  int i = blockIdx.x * 256 + threadIdx.x;
  if (i >= n4) return;
  const float4 v = reinterpret_cast<const float4*>(src)[i];
  s16x4 o; o[0] = f2bf(v.x); o[1] = f2bf(v.y); o[2] = f2bf(v.z); o[3] = f2bf(v.w);
  reinterpret_cast<s16x4*>(dst)[i] = o;
}

// ---------------- RoPE (in-place on qkv, bf16) ----------------
// q cols [0,2048): rotate + scale by 0.125*log2(e); k cols [2048,2560): rotate only.
__global__ void rope_kernel(short* __restrict__ qkv, const float* __restrict__ cosT,
                            const float* __restrict__ sinT) {
  const int r = blockIdx.y;                       // 0..4095 (b*T + t)
  const int p = blockIdx.x * 256 + threadIdx.x;   // 0..1279
  const int t = r & (T_ - 1);
  const int dd = p & 31;
  int col0; float sc;
  if (p < 1024) { int hh = p >> 5; col0 = hh * 64 + dd; sc = 0.18033688011112042f; }
  else          { int hh = (p - 1024) >> 5; col0 = KOFF + hh * 64 + dd; sc = 1.0f; }
  const float c = cosT[t * 32 + dd], s = sinT[t * 32 + dd];
  short* base = qkv + (size_t)r * NQKV;
  const float x1 = bf2f(base[col0]);
  const float x2 = bf2f(base[col0 + 32]);
  base[col0]      = f2bf((x1 * c - x2 * s) * sc);
  base[col0 + 32] = f2bf((x2 * c + x1 * s) * sc);
}

// ---------------- GEMM: C[m][n] = sum_k A[m][k] * Bm[n][k] ----------------
// m97 structure: 128x128 tile, BK=32, 4 waves (2x2), 16 MFMA/K-step/wave.
// LDS linear [128][32]; swizzle realized by permuting the global source chunk
// (slot ^= (row>>1)&3) and applying the same XOR on the ds_read side.
template <int OUT_BF16>
__global__ __launch_bounds__(256) void gemm_bt(const short* __restrict__ A,
                                               const short* __restrict__ Bm,
                                               void* __restrict__ Cm,
                                               int M, int N, int K) {
  __shared__ __attribute__((aligned(16))) short Alds[128 * 32];
  __shared__ __attribute__((aligned(16))) short Blds[128 * 32];
  const int tid = threadIdx.x;
  const int w = tid >> 6, lane = tid & 63, g = lane >> 4, l15 = lane & 15;
  const int wm = (w >> 1) * 64, wn = (w & 1) * 64;
  const int m0 = blockIdx.y * 128, n0 = blockIdx.x * 128;

  f32x4 acc[4][4] = {};

  for (int k0 = 0; k0 < K; k0 += 32) {
#pragma unroll
    for (int i = 0; i < 2; ++i) {
      int c = w * 128 + i * 64 + lane;            // chunk 0..511 (16B each)
      int row = c >> 2, slot = c & 3;
      int ks = slot ^ ((row >> 1) & 3);           // pre-swizzled source
      gload_lds16(A + (size_t)(m0 + row) * K + k0 + ks * 8,
                  Alds + (w * 128 + i * 64) * 8);
      gload_lds16(Bm + (size_t)(n0 + row) * K + k0 + ks * 8,
                  Blds + (w * 128 + i * 64) * 8);
    }
    __syncthreads();
    bf16x8 af[4], bf[4];
#pragma unroll
    for (int mi = 0; mi < 4; ++mi) {
      int ra = wm + mi * 16 + l15;
      af[mi] = *reinterpret_cast<const bf16x8*>(Alds + ra * 32 + (g ^ ((ra >> 1) & 3)) * 8);
      int rb = wn + mi * 16 + l15;
      bf[mi] = *reinterpret_cast<const bf16x8*>(Blds + rb * 32 + (g ^ ((rb >> 1) & 3)) * 8);
    }
#pragma unroll
    for (int mi = 0; mi < 4; ++mi)
#pragma unroll
      for (int ni = 0; ni < 4; ++ni)
        acc[mi][ni] = __builtin_amdgcn_mfma_f32_16x16x32_bf16(af[mi], bf[ni], acc[mi][ni], 0, 0, 0);
    __syncthreads();
  }

#pragma unroll
  for (int mi = 0; mi < 4; ++mi)
#pragma unroll
    for (int ni = 0; ni < 4; ++ni) {
      const int m = m0 + wm + mi * 16 + g * 4;    // D: row=(lane>>4)*4+reg
      const int n = n0 + wn + ni * 16 + l15;      //    col=lane&15
      if (OUT_BF16) {
        short* Cp = (short*)Cm;
#pragma unroll
        for (int r = 0; r < 4; ++r) Cp[(size_t)(m + r) * N + n] = f2bf(acc[mi][ni][r]);
      } else {
        float* Cp = (float*)Cm;
#pragma unroll
        for (int r = 0; r < 4; ++r) Cp[(size_t)(m + r) * N + n] = acc[mi][ni][r];
      }
    }
}

// ---------------- Flash attention (causal GQA) ----------------
// Block: 4 waves, Q-tile 64 rows (16/wave), KV-tile 64.
// Swapped QK^T: S^T = mfma(K, Q^T)  -> lane holds q = lane&15, j = jt*16+g*4+r.
// PV swapped:   O^T = mfma(V^T, P^T) -> per-lane scalar rescale.
__global__ __launch_bounds__(256) void attn_kernel(const short* __restrict__ qkv,
                                                   short* __restrict__ out) {
  __shared__ __attribute__((aligned(16))) short Klds[64 * 64];
  __shared__ __attribute__((aligned(16))) short Vt[64 * 64];
  __shared__ __attribute__((aligned(16))) short Plds[4][16 * 64];

  const int tid = threadIdx.x, w = tid >> 6, lane = tid & 63, g = lane >> 4, l15 = lane & 15;
  const int qh = blockIdx.y;                       // 0..63 = b*32 + h
  const int b = qh >> 5, h = qh & 31, hk = h >> 2; // G=4
  const int qt = gridDim.x - 1 - blockIdx.x;       // big-work blocks dispatch first
  const int q0 = qt * 64;
  const size_t browbase = (size_t)b * T_;

  // Q fragments live in registers: B_frag(lane,e) = Q[q=l15][kk + g*8 + e]
  const size_t qrow = browbase + q0 + w * 16 + l15;
  const bf16x8 qf0 = *reinterpret_cast<const bf16x8*>(qkv + qrow * NQKV + h * 64 + g * 8);
  const bf16x8 qf1 = *reinterpret_cast<const bf16x8*>(qkv + qrow * NQKV + h * 64 + 32 + g * 8);

  float m_run = -1e30f, l_run = 0.f;
  f32x4 o[4] = {};

  const int ntiles = qt + 1;
  for (int it = 0; it < ntiles; ++it) {
    const int kv0 = it * 64;
    // ---- stage K[64][64] via global_load_lds, source-swizzled (slot ^= j&7) ----
#pragma unroll
    for (int i = 0; i < 2; ++i) {
      int c = w * 128 + i * 64 + lane;
      int j = c >> 3, slot = c & 7;
      int ks = slot ^ (j & 7);
      gload_lds16(qkv + (browbase + kv0 + j) * NQKV + KOFF + hk * 64 + ks * 8,
                  Klds + (w * 128 + i * 64) * 8);
    }
    // ---- stage V transposed: Vt[d][j], byte ^= ((d&7)<<4) ----
#pragma unroll
    for (int i = 0; i < 2; ++i) {
      int c = tid + i * 256;
      int j = c & 63, dg = c >> 6;
      bf16x8 vv = *reinterpret_cast<const bf16x8*>(
          qkv + (browbase + kv0 + j) * NQKV + VOFF + hk * 64 + dg * 8);
#pragma unroll
      for (int e = 0; e < 8; ++e) {
        int d = dg * 8 + e;                       // d&7 == e
        Vt[d * 64 + (j ^ (e << 3))] = vv[e];
      }
    }
    __syncthreads();

    // ---- S^T = K · Q^T ----
    f32x4 sf[4];
#pragma unroll
    for (int jt = 0; jt < 4; ++jt) {
      int row = jt * 16 + l15, sw = row & 7;
      bf16x8 ka = *reinterpret_cast<const bf16x8*>(Klds + row * 64 + ((g) ^ sw) * 8);
      bf16x8 kb = *reinterpret_cast<const bf16x8*>(Klds + row * 64 + ((4 + g) ^ sw) * 8);
      f32x4 z = {};
      z = __builtin_amdgcn_mfma_f32_16x16x32_bf16(ka, qf0, z, 0, 0, 0);
      sf[jt] = __builtin_amdgcn_mfma_f32_16x16x32_bf16(kb, qf1, z, 0, 0, 0);
    }

    // ---- causal mask: only the diagonal (last) tile needs it ----
    if (kv0 == q0) {
      const int qloc = w * 16 + l15;
#pragma unroll
      for (int jt = 0; jt < 4; ++jt)
#pragma unroll
        for (int r = 0; r < 4; ++r)
          if (jt * 16 + g * 4 + r > qloc) sf[jt][r] = -1e30f;
    }

    // ---- online softmax (exp2 domain; scale folded into q) ----
    float tmax = -1e30f;
#pragma unroll
    for (int jt = 0; jt < 4; ++jt)
#pragma unroll
      for (int r = 0; r < 4; ++r) tmax = fmaxf(tmax, sf[jt][r]);
    tmax = fmaxf(tmax, __shfl_xor(tmax, 16));
    tmax = fmaxf(tmax, __shfl_xor(tmax, 32));
    const float m_new = fmaxf(m_run, tmax);
    const float corr = exp2f(m_run - m_new);
    float tsum = 0.f;
#pragma unroll
    for (int jt = 0; jt < 4; ++jt)
#pragma unroll
      for (int r = 0; r < 4; ++r) {
        float pv = exp2f(sf[jt][r] - m_new);
        sf[jt][r] = pv; tsum += pv;
      }
    tsum += __shfl_xor(tsum, 16);
    tsum += __shfl_xor(tsum, 32);
    l_run = l_run * corr + tsum;
    m_run = m_new;
#pragma unroll
    for (int dt = 0; dt < 4; ++dt) o[dt] = o[dt] * corr;

    // ---- P -> per-wave LDS (bf16, swizzled), then PV ----
    short* pl = &Plds[w][0];
    const int swq = (l15 & 7) << 4;
#pragma unroll
    for (int jt = 0; jt < 4; ++jt) {
      s16x4 pp;
#pragma unroll
      for (int r = 0; r < 4; ++r) pp[r] = f2bf(sf[jt][r]);
      int bofs = (jt * 32 + g * 8) ^ swq;         // byte offset in row
      *reinterpret_cast<s16x4*>(pl + l15 * 64 + (bofs >> 1)) = pp;
    }
    const bf16x8 pf0 = *reinterpret_cast<const bf16x8*>(pl + l15 * 64 + (((g * 16) ^ swq) >> 1));
    const bf16x8 pf1 = *reinterpret_cast<const bf16x8*>(pl + l15 * 64 + (((64 + g * 16) ^ swq) >> 1));
#pragma unroll
    for (int dt = 0; dt < 4; ++dt) {
      int row = dt * 16 + l15, sw = (row & 7) << 4;
      bf16x8 v0f = *reinterpret_cast<const bf16x8*>(Vt + row * 64 + (((g * 16) ^ sw) >> 1));
      bf16x8 v1f = *reinterpret_cast<const bf16x8*>(Vt + row * 64 + (((64 + g * 16) ^ sw) >> 1));
      o[dt] = __builtin_amdgcn_mfma_f32_16x16x32_bf16(v0f, pf0, o[dt], 0, 0, 0);
      o[dt] = __builtin_amdgcn_mfma_f32_16x16x32_bf16(v1f, pf1, o[dt], 0, 0, 0);
    }
    __syncthreads();
  }

  // ---- epilogue: out[(b,t),(h,d)] bf16; O^T: lane q=l15, d = dt*16+g*4+r ----
  const float inv_l = 1.0f / l_run;
  const size_t orow = browbase + q0 + w * 16 + l15;
#pragma unroll
  for (int dt = 0; dt < 4; ++dt) {
    s16x4 ov;
#pragma unroll
    for (int r = 0; r < 4; ++r) ov[r] = f2bf(o[dt][r] * inv_l);
    *reinterpret_cast<s16x4*>(out + orow * C_ + h * 64 + dt * 16 + g * 4) = ov;
  }
}

// ---------------- launch ----------------
extern "C" void kernel_launch(void* const* d_in, const int* in_sizes, int n_in,
                              void* d_out, int out_size, void* d_ws, size_t ws_size,
                              hipStream_t stream) {
  const float* x    = (const float*)d_in[0];
  const float* cosT = (const float*)d_in[1];
  const float* sinT = (const float*)d_in[2];
  const float* Wq   = (const float*)d_in[3];
  const float* Wkv  = (const float*)d_in[4];
  const float* Wo   = (const float*)d_in[5];

  short* xb   = (short*)d_ws;                       // 4096x2048
  short* wqkv = xb + (size_t)4096 * 2048;           // 3072x2048 (Wq rows 0..2047, Wkv 2048..3071)
  short* wob  = wqkv + (size_t)3072 * 2048;         // 2048x2048
  short* qkv  = wob + (size_t)2048 * 2048;          // 4096x3072
  short* aout = qkv + (size_t)4096 * 3072;          // 4096x2048

  cvt_kernel<<<8192, 256, 0, stream>>>(x, xb, 2097152);
  cvt_kernel<<<4096, 256, 0, stream>>>(Wq, wqkv, 1048576);
  cvt_kernel<<<2048, 256, 0, stream>>>(Wkv, wqkv + (size_t)2048 * 2048, 524288);
  cvt_kernel<<<4096, 256, 0, stream>>>(Wo, wob, 1048576);

  gemm_bt<1><<<dim3(24, 32), 256, 0, stream>>>(xb, wqkv, qkv, 4096, 3072, 2048);
  rope_kernel<<<dim3(5, 4096), 256, 0, stream>>>(qkv, cosT, sinT);
  attn_kernel<<<dim3(32, 64), 256, 0, stream>>>(qkv, aout);
  gemm_bt<0><<<dim3(16, 32), 256, 0, stream>>>(aout, wob, (float*)d_out, 4096, 2048, 2048);
}

// Round 2
// 344.505 us; speedup vs baseline: 1.2738x; 1.2738x over previous
//
#include <hip/hip_runtime.h>
#include <hip/hip_bf16.h>

// Problem constants
#define B_    2
#define T_    2048
#define C_    2048
#define H_    32
#define HKV_  8
#define DH_   64
#define NQKV  3072      // C + 2*HKV*DH
#define KOFF  2048      // k columns start
#define VOFF  2560      // v columns start

typedef __attribute__((ext_vector_type(4))) float f32x4;
typedef __attribute__((ext_vector_type(8))) short bf16x8;
typedef __attribute__((ext_vector_type(4))) short s16x4;

__device__ __forceinline__ float bf2f(short s) {
  union { unsigned u; float f; } v; v.u = ((unsigned)(unsigned short)s) << 16; return v.f;
}
__device__ __forceinline__ short f2bf(float f) {
  union { float f; unsigned u; } v; v.f = f;
  unsigned u = v.u + 0x7fffu + ((v.u >> 16) & 1u);   // RNE
  return (short)(u >> 16);
}

__device__ __forceinline__ void gload_lds16(const void* g, void* l) {
  __builtin_amdgcn_global_load_lds((const __attribute__((address_space(1))) void*)g,
                                   (__attribute__((address_space(3))) void*)l, 16, 0, 0);
}

// ---------------- fp32 -> bf16 convert ----------------
__global__ void cvt_kernel(const float* __restrict__ src, short* __restrict__ dst, int n4) {
  int i = blockIdx.x * 256 + threadIdx.x;
  if (i >= n4) return;
  const float4 v = reinterpret_cast<const float4*>(src)[i];
  s16x4 o; o[0] = f2bf(v.x); o[1] = f2bf(v.y); o[2] = f2bf(v.z); o[3] = f2bf(v.w);
  reinterpret_cast<s16x4*>(dst)[i] = o;
}

// ---------------- RoPE (in-place on qkv, bf16) ----------------
// q cols [0,2048): rotate + scale by 0.125*log2(e); k cols [2048,2560): rotate only.
__global__ void rope_kernel(short* __restrict__ qkv, const float* __restrict__ cosT,
                            const float* __restrict__ sinT) {
  const int r = blockIdx.y;                       // 0..4095 (b*T + t)
  const int p = blockIdx.x * 256 + threadIdx.x;   // 0..1279
  const int t = r & (T_ - 1);
  const int dd = p & 31;
  int col0; float sc;
  if (p < 1024) { int hh = p >> 5; col0 = hh * 64 + dd; sc = 0.18033688011112042f; }
  else          { int hh = (p - 1024) >> 5; col0 = KOFF + hh * 64 + dd; sc = 1.0f; }
  const float c = cosT[t * 32 + dd], s = sinT[t * 32 + dd];
  short* base = qkv + (size_t)r * NQKV;
  const float x1 = bf2f(base[col0]);
  const float x2 = bf2f(base[col0 + 32]);
  base[col0]      = f2bf((x1 * c - x2 * s) * sc);
  base[col0 + 32] = f2bf((x2 * c + x1 * s) * sc);
}

// ---------------- V transpose: vT[b][hk][d][t] <- V[t][d] ----------------
__global__ void vtrans_kernel(const short* __restrict__ qkv, short* __restrict__ vT) {
  __shared__ short tile[64][72];                  // +8 pad
  const int tid = threadIdx.x;
  const int tt = blockIdx.x, bh = blockIdx.y;     // tt: 64-token tile; bh = b*8+hk
  const int b = bh >> 3, hk = bh & 7;
#pragma unroll
  for (int i = 0; i < 2; ++i) {
    int c = tid + i * 256;
    int r = c >> 3, s = c & 7;
    bf16x8 v = *reinterpret_cast<const bf16x8*>(
        qkv + ((size_t)(b * T_ + tt * 64 + r)) * NQKV + VOFF + hk * 64 + s * 8);
#pragma unroll
    for (int e = 0; e < 8; ++e) tile[s * 8 + e][r] = v[e];
  }
  __syncthreads();
#pragma unroll
  for (int i = 0; i < 2; ++i) {
    int c = tid + i * 256;
    int d = c >> 3, s = c & 7;
    bf16x8 o;
#pragma unroll
    for (int e = 0; e < 8; ++e) o[e] = tile[d][s * 8 + e];
    *reinterpret_cast<bf16x8*>(vT + ((size_t)bh * 64 + d) * T_ + tt * 64 + s * 8) = o;
  }
}

// ---------------- GEMM: C[m][n] = sum_k A[m][k] * Bm[n][k] ----------------
template <int OUT_BF16>
__global__ __launch_bounds__(256) void gemm_bt(const short* __restrict__ A,
                                               const short* __restrict__ Bm,
                                               void* __restrict__ Cm,
                                               int M, int N, int K) {
  __shared__ __attribute__((aligned(16))) short Alds[128 * 32];
  __shared__ __attribute__((aligned(16))) short Blds[128 * 32];
  const int tid = threadIdx.x;
  const int w = tid >> 6, lane = tid & 63, g = lane >> 4, l15 = lane & 15;
  const int wm = (w >> 1) * 64, wn = (w & 1) * 64;
  const int m0 = blockIdx.y * 128, n0 = blockIdx.x * 128;

  f32x4 acc[4][4] = {};

  for (int k0 = 0; k0 < K; k0 += 32) {
#pragma unroll
    for (int i = 0; i < 2; ++i) {
      int c = w * 128 + i * 64 + lane;            // chunk 0..511 (16B each)
      int row = c >> 2, slot = c & 3;
      int ks = slot ^ ((row >> 1) & 3);           // pre-swizzled source
      gload_lds16(A + (size_t)(m0 + row) * K + k0 + ks * 8,
                  Alds + (w * 128 + i * 64) * 8);
      gload_lds16(Bm + (size_t)(n0 + row) * K + k0 + ks * 8,
                  Blds + (w * 128 + i * 64) * 8);
    }
    __syncthreads();
    bf16x8 af[4], bf[4];
#pragma unroll
    for (int mi = 0; mi < 4; ++mi) {
      int ra = wm + mi * 16 + l15;
      af[mi] = *reinterpret_cast<const bf16x8*>(Alds + ra * 32 + (g ^ ((ra >> 1) & 3)) * 8);
      int rb = wn + mi * 16 + l15;
      bf[mi] = *reinterpret_cast<const bf16x8*>(Blds + rb * 32 + (g ^ ((rb >> 1) & 3)) * 8);
    }
#pragma unroll
    for (int mi = 0; mi < 4; ++mi)
#pragma unroll
      for (int ni = 0; ni < 4; ++ni)
        acc[mi][ni] = __builtin_amdgcn_mfma_f32_16x16x32_bf16(af[mi], bf[ni], acc[mi][ni], 0, 0, 0);
    __syncthreads();
  }

#pragma unroll
  for (int mi = 0; mi < 4; ++mi)
#pragma unroll
    for (int ni = 0; ni < 4; ++ni) {
      const int m = m0 + wm + mi * 16 + g * 4;    // D: row=(lane>>4)*4+reg
      const int n = n0 + wn + ni * 16 + l15;      //    col=lane&15
      if (OUT_BF16) {
        short* Cp = (short*)Cm;
#pragma unroll
        for (int r = 0; r < 4; ++r) Cp[(size_t)(m + r) * N + n] = f2bf(acc[mi][ni][r]);
      } else {
        float* Cp = (float*)Cm;
#pragma unroll
        for (int r = 0; r < 4; ++r) Cp[(size_t)(m + r) * N + n] = acc[mi][ni][r];
      }
    }
}

// ---------------- Flash attention (causal GQA), balanced 2-tile blocks ----------------
// Block p (of 16) handles Q-tiles A=p and B=31-p (64 rows each) in ONE kv loop
// of nt=32-p steps: A active while t<=p. Per-wave 16 q-rows per tile.
// Swapped QK^T: S^T = mfma(K, Q^T); PV: O^T = mfma(V^T, P^T).
// K and V^T both staged via global_load_lds (double-buffered, src-swizzled).
__global__ __launch_bounds__(256, 4) void attn_kernel(const short* __restrict__ qkv,
                                                      const short* __restrict__ vT,
                                                      short* __restrict__ out) {
  __shared__ __attribute__((aligned(16))) short Klds[2][64 * 64];
  __shared__ __attribute__((aligned(16))) short Vlds[2][64 * 64];
  __shared__ __attribute__((aligned(16))) short Plds[4][16 * 64];

  const int tid = threadIdx.x, w = tid >> 6, lane = tid & 63, g = lane >> 4, l15 = lane & 15;
  const int qh = blockIdx.y;                       // b*32 + h
  const int b = qh >> 5, h = qh & 31, hk = h >> 2;
  const int p = blockIdx.x;                        // 0..15
  const int qtB = 31 - p;
  const int nt = 32 - p;
  const size_t browbase = (size_t)b * T_;

  // Q fragments (B-operand: col q = lane&15, k = (lane>>4)*8+e)
  const size_t qrowA = browbase + p * 64 + w * 16 + l15;
  const size_t qrowB = browbase + qtB * 64 + w * 16 + l15;
  const bf16x8 qA0 = *reinterpret_cast<const bf16x8*>(qkv + qrowA * NQKV + h * 64 + g * 8);
  const bf16x8 qA1 = *reinterpret_cast<const bf16x8*>(qkv + qrowA * NQKV + h * 64 + 32 + g * 8);
  const bf16x8 qB0 = *reinterpret_cast<const bf16x8*>(qkv + qrowB * NQKV + h * 64 + g * 8);
  const bf16x8 qB1 = *reinterpret_cast<const bf16x8*>(qkv + qrowB * NQKV + h * 64 + 32 + g * 8);

  const short* kgbase = qkv + browbase * NQKV + KOFF + hk * 64;
  const short* vgbase = vT + ((size_t)(b * HKV_ + hk)) * 64 * T_;

  float mA = -1e30f, lA = 0.f, mB = -1e30f, lB = 0.f;
  f32x4 oA[4] = {}, oB[4] = {};

  short* const pl = &Plds[w][0];
  const int swq = (l15 & 7) << 4;
  const int qloc = w * 16 + l15;

  auto STAGE = [&](int kt, int buf) {
    const int kv0 = kt * 64;
#pragma unroll
    for (int i = 0; i < 2; ++i) {
      const int c = w * 128 + i * 64 + lane;       // 0..511 16B chunks
      const int j = c >> 3, slot = c & 7;
      gload_lds16(kgbase + (size_t)(kv0 + j) * NQKV + (slot ^ (j & 7)) * 8,
                  &Klds[buf][(w * 128 + i * 64) * 8]);
      gload_lds16(vgbase + (size_t)j * T_ + kv0 + (slot ^ (j & 7)) * 8,
                  &Vlds[buf][(w * 128 + i * 64) * 8]);
    }
  };

  auto softmax_pack = [&](f32x4* sf, float& m_run, float& l_run,
                          bf16x8& pf0, bf16x8& pf1) -> float {
    float tmax = -1e30f;
#pragma unroll
    for (int jt = 0; jt < 4; ++jt)
#pragma unroll
      for (int r = 0; r < 4; ++r) tmax = fmaxf(tmax, sf[jt][r]);
    tmax = fmaxf(tmax, __shfl_xor(tmax, 16));
    tmax = fmaxf(tmax, __shfl_xor(tmax, 32));
    const float m_new = fmaxf(m_run, tmax);
    const float corr = exp2f(m_run - m_new);
    float tsum = 0.f;
#pragma unroll
    for (int jt = 0; jt < 4; ++jt)
#pragma unroll
      for (int r = 0; r < 4; ++r) {
        float pv = exp2f(sf[jt][r] - m_new);
        sf[jt][r] = pv; tsum += pv;
      }
    tsum += __shfl_xor(tsum, 16);
    tsum += __shfl_xor(tsum, 32);
    l_run = l_run * corr + tsum;
    m_run = m_new;
#pragma unroll
    for (int jt = 0; jt < 4; ++jt) {
      s16x4 pp;
#pragma unroll
      for (int r = 0; r < 4; ++r) pp[r] = f2bf(sf[jt][r]);
      *reinterpret_cast<s16x4*>(pl + l15 * 64 + (((jt * 32 + g * 8) ^ swq) >> 1)) = pp;
    }
    pf0 = *reinterpret_cast<const bf16x8*>(pl + l15 * 64 + (((g * 16) ^ swq) >> 1));
    pf1 = *reinterpret_cast<const bf16x8*>(pl + l15 * 64 + (((64 + g * 16) ^ swq) >> 1));
    return corr;
  };

  STAGE(0, 0);
  __syncthreads();

  for (int t = 0; t < nt; ++t) {
    const int cur = t & 1;
    if (t + 1 < nt) STAGE(t + 1, cur ^ 1);        // prefetch next tile into other buffer
    const short* Kc = &Klds[cur][0];
    const short* Vc = &Vlds[cur][0];
    const bool doA = (t <= p);

    f32x4 s[4];
    // ---- S^T tile B (always active) ----
#pragma unroll
    for (int jt = 0; jt < 4; ++jt) {
      const int row = jt * 16 + l15, sw = row & 7;
      bf16x8 ka = *reinterpret_cast<const bf16x8*>(Kc + row * 64 + (g ^ sw) * 8);
      bf16x8 kb = *reinterpret_cast<const bf16x8*>(Kc + row * 64 + ((4 + g) ^ sw) * 8);
      f32x4 z = {};
      z = __builtin_amdgcn_mfma_f32_16x16x32_bf16(ka, qB0, z, 0, 0, 0);
      s[jt] = __builtin_amdgcn_mfma_f32_16x16x32_bf16(kb, qB1, z, 0, 0, 0);
    }
    if (t == nt - 1) {                            // diagonal tile for B
#pragma unroll
      for (int jt = 0; jt < 4; ++jt)
#pragma unroll
        for (int r = 0; r < 4; ++r)
          if (jt * 16 + g * 4 + r > qloc) s[jt][r] = -1e30f;
    }
    bf16x8 pB0, pB1;
    const float corrB = softmax_pack(s, mB, lB, pB0, pB1);
#pragma unroll
    for (int dt = 0; dt < 4; ++dt) oB[dt] *= corrB;

    // ---- S^T tile A (active while t <= p) ----
    bf16x8 pA0, pA1;
    if (doA) {
#pragma unroll
      for (int jt = 0; jt < 4; ++jt) {
        const int row = jt * 16 + l15, sw = row & 7;
        bf16x8 ka = *reinterpret_cast<const bf16x8*>(Kc + row * 64 + (g ^ sw) * 8);
        bf16x8 kb = *reinterpret_cast<const bf16x8*>(Kc + row * 64 + ((4 + g) ^ sw) * 8);
        f32x4 z = {};
        z = __builtin_amdgcn_mfma_f32_16x16x32_bf16(ka, qA0, z, 0, 0, 0);
        s[jt] = __builtin_amdgcn_mfma_f32_16x16x32_bf16(kb, qA1, z, 0, 0, 0);
      }
      if (t == p) {                               // diagonal tile for A
#pragma unroll
        for (int jt = 0; jt < 4; ++jt)
#pragma unroll
          for (int r = 0; r < 4; ++r)
            if (jt * 16 + g * 4 + r > qloc) s[jt][r] = -1e30f;
      }
      const float corrA = softmax_pack(s, mA, lA, pA0, pA1);
#pragma unroll
      for (int dt = 0; dt < 4; ++dt) oA[dt] *= corrA;
    }

    // ---- PV (V^T frags read once, feed both tiles) ----
#pragma unroll
    for (int dt = 0; dt < 4; ++dt) {
      const int row = dt * 16 + l15, sw = row & 7;
      bf16x8 v0 = *reinterpret_cast<const bf16x8*>(Vc + row * 64 + (g ^ sw) * 8);
      bf16x8 v1 = *reinterpret_cast<const bf16x8*>(Vc + row * 64 + ((4 + g) ^ sw) * 8);
      oB[dt] = __builtin_amdgcn_mfma_f32_16x16x32_bf16(v0, pB0, oB[dt], 0, 0, 0);
      oB[dt] = __builtin_amdgcn_mfma_f32_16x16x32_bf16(v1, pB1, oB[dt], 0, 0, 0);
      if (doA) {
        oA[dt] = __builtin_amdgcn_mfma_f32_16x16x32_bf16(v0, pA0, oA[dt], 0, 0, 0);
        oA[dt] = __builtin_amdgcn_mfma_f32_16x16x32_bf16(v1, pA1, oA[dt], 0, 0, 0);
      }
    }
    __syncthreads();
  }

  // ---- epilogue: O^T lane q=l15, d = dt*16+g*4+r ----
  {
    const float inv = 1.0f / lA;
#pragma unroll
    for (int dt = 0; dt < 4; ++dt) {
      s16x4 ov;
#pragma unroll
      for (int r = 0; r < 4; ++r) ov[r] = f2bf(oA[dt][r] * inv);
      *reinterpret_cast<s16x4*>(out + qrowA * C_ + h * 64 + dt * 16 + g * 4) = ov;
    }
  }
  {
    const float inv = 1.0f / lB;
#pragma unroll
    for (int dt = 0; dt < 4; ++dt) {
      s16x4 ov;
#pragma unroll
      for (int r = 0; r < 4; ++r) ov[r] = f2bf(oB[dt][r] * inv);
      *reinterpret_cast<s16x4*>(out + qrowB * C_ + h * 64 + dt * 16 + g * 4) = ov;
    }
  }
}

// ---------------- launch ----------------
extern "C" void kernel_launch(void* const* d_in, const int* in_sizes, int n_in,
                              void* d_out, int out_size, void* d_ws, size_t ws_size,
                              hipStream_t stream) {
  const float* x    = (const float*)d_in[0];
  const float* cosT = (const float*)d_in[1];
  const float* sinT = (const float*)d_in[2];
  const float* Wq   = (const float*)d_in[3];
  const float* Wkv  = (const float*)d_in[4];
  const float* Wo   = (const float*)d_in[5];

  short* xb   = (short*)d_ws;                       // 4096x2048 (dead after gemm_qkv)
  short* wqkv = xb + (size_t)4096 * 2048;           // 3072x2048
  short* wob  = wqkv + (size_t)3072 * 2048;         // 2048x2048
  short* qkv  = wob + (size_t)2048 * 2048;          // 4096x3072
  short* aout = qkv + (size_t)4096 * 3072;          // 4096x2048
  short* vTb  = xb;                                 // 2x8x64x2048 overlays xb (safe: vtrans runs after gemm_qkv)

  cvt_kernel<<<8192, 256, 0, stream>>>(x, xb, 2097152);
  cvt_kernel<<<4096, 256, 0, stream>>>(Wq, wqkv, 1048576);
  cvt_kernel<<<2048, 256, 0, stream>>>(Wkv, wqkv + (size_t)2048 * 2048, 524288);
  cvt_kernel<<<4096, 256, 0, stream>>>(Wo, wob, 1048576);

  gemm_bt<1><<<dim3(24, 32), 256, 0, stream>>>(xb, wqkv, qkv, 4096, 3072, 2048);
  rope_kernel<<<dim3(5, 4096), 256, 0, stream>>>(qkv, cosT, sinT);
  vtrans_kernel<<<dim3(32, 16), 256, 0, stream>>>(qkv, vTb);
  attn_kernel<<<dim3(16, 64), 256, 0, stream>>>(qkv, vTb, aout);
  gemm_bt<0><<<dim3(16, 32), 256, 0, stream>>>(aout, wob, (float*)d_out, 4096, 2048, 2048);
}